// Round 9
// baseline (463.394 us; speedup 1.0000x reference)
//
#include <hip/hip_runtime.h>

// Problem constants
#define NB 4
#define NA 3
#define NS 1024
#define NHID 768
#define NHEADS 12
#define HD 64

typedef __bf16 bf16_t;
typedef __bf16 bf16x8 __attribute__((ext_vector_type(8)));
typedef float f32x4 __attribute__((ext_vector_type(4)));

#define MFMA(a, b, c) __builtin_amdgcn_mfma_f32_16x16x32_bf16(a, b, c, 0, 0, 0)

static __device__ __forceinline__ bf16x8 load8(const bf16_t* p) {
    return *reinterpret_cast<const bf16x8*>(p);
}

// async global->LDS, 16B per lane. LDS dest = wave-uniform base + lane*16.
typedef __attribute__((address_space(3))) unsigned int u32_lds;
typedef __attribute__((address_space(1))) unsigned int u32_glb;
static __device__ __forceinline__ void gl_lds16(const void* g, void* lds_base_uniform) {
    __builtin_amdgcn_global_load_lds((const u32_glb*)g, (u32_lds*)lds_base_uniform, 16, 0, 0);
}

static __device__ __forceinline__ bf16x8 cvt8(f32x4 lo, f32x4 hi) {
    bf16x8 r;
    r[0] = (bf16_t)lo[0]; r[1] = (bf16_t)lo[1]; r[2] = (bf16_t)lo[2]; r[3] = (bf16_t)lo[3];
    r[4] = (bf16_t)hi[0]; r[5] = (bf16_t)hi[1]; r[6] = (bf16_t)hi[2]; r[7] = (bf16_t)hi[3];
    return r;
}

// ---------------------------------------------------------------------------
// Projection GEMM, 128x128 tile, BK=32, 4 waves (2x2) of 64x64 (4x4 MFMA).
// R9: DOUBLE-BUFFERED K-loop (attention-style: stage(next) before
// compute(cur), single barrier per iter) — R8 measured this kernel purely
// latency-bound (Mfma 6.8%, VALU 11.9%, HBM 8.7%): zero-overlap staging
// exposed full HBM latency every k-iter. Staging pointers hoisted
// (advance by 32 elems per stage; stage called once per k-step in order).
// XCD swizzle: all NT n-tiles of one m-slab on one XCD (bid&7).
// MODE 0: Q bf16 [b][h][s][d]
// MODE 1: fused KV, N=1536: n<768 -> K [b][h][a][s][d]; n>=768 -> VT
// MODE 3: fp32 outf = gemm + bias + resid  (A is bf16 AT)
// ---------------------------------------------------------------------------
template <int MODE, int NT>
__global__ __launch_bounds__(256) void proj_gemm(
    const void* __restrict__ Xv,
    const float* __restrict__ W0, const float* __restrict__ W1,
    const float* __restrict__ bias0, const float* __restrict__ bias1,
    const float* __restrict__ resid,
    bf16_t* __restrict__ out0, bf16_t* __restrict__ out1,
    float* __restrict__ outf)
{
    constexpr bool AF32 = (MODE != 3);
    constexpr int ASZ   = AF32 ? 16384 : 8192;
    constexpr int BUFSZ = ASZ + 16384;
    __shared__ __align__(16) char smem[2 * BUFSZ];

    const int t = threadIdx.x;
    const int lane = t & 63, w = t >> 6;
    const int quad = lane >> 4, l15 = lane & 15;
    const int wm = w >> 1, wn = w & 1;

    // XCD-aware swizzle (bijective index remap)
    const int bid = blockIdx.x;
    const int xcd = bid & 7, jj = bid >> 3;
    const int n_t = jj % NT, slab = jj / NT;
    const int m0 = (slab * 8 + xcd) * 128;
    const int n0 = n_t * 128;

    // B source select (KV fusion)
    const float* Wsel = (MODE == 1 && n0 >= 768) ? W1 : W0;
    const int n0b = (MODE == 1 && n0 >= 768) ? n0 - 768 : n0;

    // hoisted staging pointers (half-plane pattern, R5-proven)
    const float* Apf[4];
    const bf16_t* Apb[2];
    const float* Bpf[4];
    if constexpr (AF32) {
        const float* X = (const float*)Xv;
#pragma unroll
        for (int i = 0; i < 4; i++) {
            int g = w * 4 + i, h = g & 1, gp = g >> 1;
            Apf[i] = X + (size_t)(m0 + gp * 16 + l15) * NHID + quad * 8 + h * 4;
        }
    } else {
        const bf16_t* X = (const bf16_t*)Xv;
#pragma unroll
        for (int i = 0; i < 2; i++) {
            int g = w * 2 + i;
            Apb[i] = X + (size_t)(m0 + g * 16 + l15) * NHID + quad * 8;
        }
    }
#pragma unroll
    for (int i = 0; i < 4; i++) {
        int g = w * 4 + i, h = g & 1, gp = g >> 1;
        Bpf[i] = Wsel + (size_t)(n0b + gp * 16 + l15) * NHID + quad * 8 + h * 4;
    }

    // stage one 32-k tile into buffer `base`, advancing pointers
    auto stage = [&](char* base) {
        char* Ab = base;
        char* Bb = base + ASZ;
        if constexpr (AF32) {
#pragma unroll
            for (int i = 0; i < 4; i++) {
                int g = w * 4 + i, h = g & 1, gp = g >> 1;
                gl_lds16(Apf[i], Ab + h * 8192 + gp * 1024);
                Apf[i] += 32;
            }
        } else {
#pragma unroll
            for (int i = 0; i < 2; i++) {
                int g = w * 2 + i;
                gl_lds16(Apb[i], Ab + g * 1024);
                Apb[i] += 32;
            }
        }
#pragma unroll
        for (int i = 0; i < 4; i++) {
            int g = w * 4 + i, h = g & 1, gp = g >> 1;
            gl_lds16(Bpf[i], Bb + h * 8192 + gp * 1024);
            Bpf[i] += 32;
        }
    };

    f32x4 acc[4][4];
#pragma unroll
    for (int i = 0; i < 4; i++)
#pragma unroll
        for (int j = 0; j < 4; j++) acc[i][j] = 0.0f;

    constexpr int KITER = NHID / 32;   // 24
    stage(smem);
    __syncthreads();

    for (int it = 0; it < KITER; ++it) {
        char* cur = smem + (it & 1) * BUFSZ;
        if (it + 1 < KITER) stage(smem + ((it + 1) & 1) * BUFSZ);

        char* Ab = cur;
        char* Bb = cur + ASZ;
        bf16x8 af[4], bfr[4];
#pragma unroll
        for (int i = 0; i < 4; i++) {
            int mt = wm * 4 + i;
            if constexpr (AF32) {
                f32x4 lo = *(const f32x4*)(Ab + (mt * 64 + lane) * 16);
                f32x4 hi = *(const f32x4*)(Ab + 8192 + (mt * 64 + lane) * 16);
                af[i] = cvt8(lo, hi);
            } else {
                af[i] = *(const bf16x8*)(Ab + (mt * 64 + lane) * 16);
            }
        }
#pragma unroll
        for (int j = 0; j < 4; j++) {
            int nt = wn * 4 + j;
            f32x4 lo = *(const f32x4*)(Bb + (nt * 64 + lane) * 16);
            f32x4 hi = *(const f32x4*)(Bb + 8192 + (nt * 64 + lane) * 16);
            bfr[j] = cvt8(lo, hi);
        }
#pragma unroll
        for (int i = 0; i < 4; i++)
#pragma unroll
            for (int j = 0; j < 4; j++)
                acc[i][j] = MFMA(af[i], bfr[j], acc[i][j]);
        __syncthreads();   // drains next-tile staging; guards buffer reuse
    }

#pragma unroll
    for (int i = 0; i < 4; i++) {
#pragma unroll
        for (int j = 0; j < 4; j++) {
            const int n = n0 + wn * 64 + j * 16 + l15;
            float bn;
            if (MODE == 1) bn = (n < 768) ? bias0[n] : bias1[n - 768];
            else           bn = bias0[n];
#pragma unroll
            for (int rg = 0; rg < 4; rg++) {
                const int m = m0 + wm * 64 + i * 16 + quad * 4 + rg;
                float v = acc[i][j][rg] + bn;
                if (MODE == 0) {
                    int b = m >> 10, s = m & 1023, hh = n >> 6, d = n & 63;
                    out0[(((size_t)(b * NHEADS + hh) * NS) + s) * HD + d] = (bf16_t)v;
                } else if (MODE == 1) {
                    int b = m / (NA * NS);
                    int rem = m - b * (NA * NS);
                    int a = rem >> 10, s = rem & 1023;
                    if (n < 768) {
                        int hh = n >> 6, d = n & 63;
                        out0[((((size_t)(b * NHEADS + hh) * NA + a) * NS) + s) * HD + d] = (bf16_t)v;
                    } else {
                        int hh = (n - 768) >> 6, d = (n - 768) & 63;
                        out1[((((size_t)(b * NHEADS + hh) * NA + a) * HD) + d) * NS + s] = (bf16_t)v;
                    }
                } else {
                    v += resid[(size_t)m * NHID + n];
                    outf[(size_t)m * NHID + n] = v;
                }
            }
        }
    }
}

// ---------------------------------------------------------------------------
// Attention: block = (bh, 64 q-rows); each WAVE owns a distinct 16-row
// q-tile (qt = (qblk<<2)|w — the R6/R7 coverage bug, fixed in R8).
// s-tiles of 32 double-buffered via global_load_lds; barrier after compute.
// R9: staging addresses hoisted out of the s-loop (pointer-advance; proven
// byte-equivalent by R6==R7). XCD swizzle keeps one bh per XCD.
// ---------------------------------------------------------------------------
__global__ __launch_bounds__(256) void attn_kernel(
    const bf16_t* __restrict__ Q, const bf16_t* __restrict__ K,
    const bf16_t* __restrict__ VT, bf16_t* __restrict__ AT)
{
    __shared__ __align__(16) char kv[2 * 24576];        // 2 x (K 12K + VT 12K)
    __shared__ __align__(16) bf16_t Pbuf[4][3][16 * 56];

    const int t    = threadIdx.x;
    const int w    = t >> 6, lane = t & 63;
    const int quad = lane >> 4, l15 = lane & 15;

    int bh, qt;
    if (gridDim.x == 768) {           // full launch: XCD-local bh
        int xcd = blockIdx.x & 7, j = blockIdx.x >> 3;
        bh = (j >> 4) * 8 + xcd;      // 6 slabs x 8 xcd = 48
        qt = ((j & 15) << 2) | w;     // wave-level q-tiling: 0..63
    } else {                          // per-batch fallback
        bh = blockIdx.x >> 4;
        qt = ((blockIdx.x & 15) << 2) | w;
    }
    const int b  = bh / NHEADS, h = bh - b * NHEADS;
    const int q0 = qt * 16;

    const bf16_t* Qb = Q + ((size_t)bh * NS + q0) * HD;
    bf16x8 qf0 = load8(Qb + l15 * HD + quad * 8);
    bf16x8 qf1 = load8(Qb + l15 * HD + quad * 8 + 32);

    // hoisted staging pointers: 6 groups per wave (24 total: 12 K + 12 VT)
    const char* gp[6];
    int gdelta[6], loff[6];
#pragma unroll
    for (int i = 0; i < 6; i++) {
        int g = w * 6 + i;
        loff[i] = g >= 12 ? 12288 + (g - 12) * 1024 : g * 1024;
        if (g < 12) {   // K: a|j|dh
            int a = g >> 2, j = (g >> 1) & 1, dh = g & 1;
            gp[i] = (const char*)(K + ((size_t)(bh * NA + a) * NS + j * 16 + l15) * HD
                                  + dh * 32 + quad * 8);
            gdelta[i] = 32 * HD * 2;  // +32 s-rows (bytes)
        } else {        // VT: a|dt
            int gi = g - 12;
            int a = gi >> 2, dt = gi & 3;
            gp[i] = (const char*)(VT + ((size_t)(bh * NA + a) * HD + dt * 16 + l15) * NS
                                  + quad * 8);
            gdelta[i] = 32 * 2;       // +32 s-cols (bytes)
        }
    }

    auto stage = [&](int buf) {
#pragma unroll
        for (int i = 0; i < 6; i++) {
            gl_lds16(gp[i], kv + buf * 24576 + loff[i]);
            gp[i] += gdelta[i];
        }
    };

    f32x4 acc[4];
#pragma unroll
    for (int dt = 0; dt < 4; dt++) acc[dt] = 0.0f;

    const float KS = 0.18033688011112042f;  // (1/8) * log2(e)

    stage(0);
    __syncthreads();

    for (int it = 0; it < 32; ++it) {
        if (it + 1 < 32) stage((it + 1) & 1);

        const char* base = kv + (it & 1) * 24576;
        f32x4 sc[3][2];
#pragma unroll
        for (int a = 0; a < 3; a++) {
#pragma unroll
            for (int j = 0; j < 2; j++) {
                bf16x8 klo = *(const bf16x8*)(base + ((a * 4 + j * 2 + 0) * 64 + lane) * 16);
                bf16x8 khi = *(const bf16x8*)(base + ((a * 4 + j * 2 + 1) * 64 + lane) * 16);
                f32x4 z = 0.0f;
                f32x4 c0 = MFMA(qf0, klo, z);
                sc[a][j] = MFMA(qf1, khi, c0);
            }
        }
        // 3-exp softmax over adapters, write P to LDS (C->A layout transform)
#pragma unroll
        for (int j = 0; j < 2; j++) {
#pragma unroll
            for (int rg = 0; rg < 4; rg++) {
                float x0 = sc[0][j][rg], x1 = sc[1][j][rg], x2 = sc[2][j][rg];
                float mx = fmaxf(x0, fmaxf(x1, x2));
                float e0 = __builtin_amdgcn_exp2f((x0 - mx) * KS);
                float e1 = __builtin_amdgcn_exp2f((x1 - mx) * KS);
                float e2 = __builtin_amdgcn_exp2f((x2 - mx) * KS);
                float inv = __builtin_amdgcn_rcpf(e0 + e1 + e2);
                int pi = (quad * 4 + rg) * 56 + j * 16 + l15;
                Pbuf[w][0][pi] = (bf16_t)(e0 * inv);
                Pbuf[w][1][pi] = (bf16_t)(e1 * inv);
                Pbuf[w][2][pi] = (bf16_t)(e2 * inv);
            }
        }
        // wave-private LDS RAW: drain DS pipe (also compiler fence)
        asm volatile("s_waitcnt lgkmcnt(0)" ::: "memory");
#pragma unroll
        for (int a = 0; a < 3; a++) {
            bf16x8 pf = load8(&Pbuf[w][a][l15 * 56 + quad * 8]);
#pragma unroll
            for (int dt = 0; dt < 4; dt++) {
                bf16x8 vf = *(const bf16x8*)(base + 12288 + ((a * 4 + dt) * 64 + lane) * 16);
                acc[dt] = MFMA(pf, vf, acc[dt]);
            }
        }
        __syncthreads();  // guards buffer reuse; drains it+1 staging
    }

    bf16_t* Ob = AT + (size_t)b * NS * NHID;
#pragma unroll
    for (int dt = 0; dt < 4; dt++) {
#pragma unroll
        for (int rg = 0; rg < 4; rg++) {
            int qq = q0 + quad * 4 + rg;
            Ob[(size_t)qq * NHID + h * HD + dt * 16 + l15] = (bf16_t)acc[dt][rg];
        }
    }
}

// ---------------------------------------------------------------------------
// LayerNorm over rows of X (fp32, [4096,768]), IN PLACE.
// ---------------------------------------------------------------------------
__global__ __launch_bounds__(256) void ln_kernel(
    float* __restrict__ X, const float* __restrict__ gamma,
    const float* __restrict__ beta)
{
    const int row = blockIdx.x;
    const int t = threadIdx.x;
    float* x = X + (size_t)row * NHID;
    float v0 = x[t], v1 = x[t + 256], v2 = x[t + 512];
    float s  = v0 + v1 + v2;
    float s2 = v0 * v0 + v1 * v1 + v2 * v2;
#pragma unroll
    for (int off = 32; off > 0; off >>= 1) {
        s  += __shfl_down(s, off);
        s2 += __shfl_down(s2, off);
    }
    __shared__ float red[8];
    const int w = t >> 6, lane = t & 63;
    if (lane == 0) { red[w] = s; red[4 + w] = s2; }
    __syncthreads();
    s  = red[0] + red[1] + red[2] + red[3];
    s2 = red[4] + red[5] + red[6] + red[7];
    float mu  = s * (1.0f / NHID);
    float var = s2 * (1.0f / NHID) - mu * mu;
    float rs  = rsqrtf(fmaxf(var, 0.0f) + 1e-5f);
    x[t]       = (v0 - mu) * rs * gamma[t]       + beta[t];
    x[t + 256] = (v1 - mu) * rs * gamma[t + 256] + beta[t + 256];
    x[t + 512] = (v2 - mu) * rs * gamma[t + 512] + beta[t + 512];
}

// avg_weights == 1/3 identically (softmax over adapter axis sums to 1).
__global__ __launch_bounds__(256) void fill_third(float* __restrict__ p)
{
    const int i = blockIdx.x * 256 + threadIdx.x;
    f32x4 v = { 1.0f / 3.0f, 1.0f / 3.0f, 1.0f / 3.0f, 1.0f / 3.0f };
    *reinterpret_cast<f32x4*>(p + (size_t)i * 4) = v;
}

// ---------------------------------------------------------------------------
// out0 [0,12.58MB) fp32: O-proj X -> LN in place. out1: bf16 scratch
// (Q 6.29 + AT 6.29 MB), overwritten by fill_third last. ws: K + VT 37.75MB.
// ---------------------------------------------------------------------------
extern "C" void kernel_launch(void* const* d_in, const int* in_sizes, int n_in,
                              void* d_out, int out_size, void* d_ws, size_t ws_size,
                              hipStream_t stream)
{
    (void)in_sizes; (void)n_in; (void)out_size;
    const float* query = (const float*)d_in[0];
    const float* adapt = (const float*)d_in[1];
    const float* Wq    = (const float*)d_in[2];
    const float* bq    = (const float*)d_in[3];
    const float* Wk    = (const float*)d_in[4];
    const float* bk    = (const float*)d_in[5];
    const float* Wv    = (const float*)d_in[6];
    const float* bv    = (const float*)d_in[7];
    const float* Wo    = (const float*)d_in[8];
    const float* bo    = (const float*)d_in[9];
    const float* gamma = (const float*)d_in[10];
    const float* beta  = (const float*)d_in[11];

    float*  out0  = (float*)d_out;            // 3,145,728 fp32
    float*  out1f = out0 + 3145728;           // 4,194,304 fp32
    bf16_t* out1b = (bf16_t*)out1f;

    dim3 blk(256);

    if (ws_size >= (size_t)37748736) {
        bf16_t* Kw  = (bf16_t*)d_ws;
        bf16_t* VTw = (bf16_t*)((char*)d_ws + 18874368);
        bf16_t* Qw  = out1b;
        bf16_t* ATw = out1b + 3145728;
        // Q: M=4096 (32 mt), N=768 (6 nt) -> 192 blocks
        proj_gemm<0, 6><<<dim3(192), blk, 0, stream>>>(
            query, Wq, nullptr, bq, nullptr, nullptr, Qw, nullptr, nullptr);
        // fused KV: M=12288 (96 mt), N=1536 (12 nt) -> 1152 blocks
        proj_gemm<1, 12><<<dim3(1152), blk, 0, stream>>>(
            adapt, Wk, Wv, bk, bv, nullptr, Kw, VTw, nullptr);
        attn_kernel<<<dim3(768), blk, 0, stream>>>(Qw, Kw, VTw, ATw);
        // O: bf16 A, fp32 out + residual
        proj_gemm<3, 6><<<dim3(192), blk, 0, stream>>>(
            ATw, Wo, nullptr, bo, nullptr, query, nullptr, nullptr, out0);
    } else {
        // per-batch, zero-workspace fallback (scratch inside out1)
        bf16_t* Qc  = out1b;                  //   786,432 bf16
        bf16_t* ATc = out1b + 786432;         //   786,432 bf16
        bf16_t* Kc  = out1b + 1572864;        // 2,359,296 bf16
        bf16_t* VTc = out1b + 3932160;        // 2,359,296 bf16
        for (int b = 0; b < NB; b++) {
            const float* qb = query + (size_t)b * NS * NHID;
            const float* ab = adapt + (size_t)b * NA * NS * NHID;
            proj_gemm<0, 6><<<dim3(48), blk, 0, stream>>>(
                qb, Wq, nullptr, bq, nullptr, nullptr, Qc, nullptr, nullptr);
            proj_gemm<1, 12><<<dim3(288), blk, 0, stream>>>(
                ab, Wk, Wv, bk, bv, nullptr, Kc, VTc, nullptr);
            attn_kernel<<<dim3(192), blk, 0, stream>>>(Qc, Kc, VTc, ATc);
            proj_gemm<3, 6><<<dim3(48), blk, 0, stream>>>(
                ATc, Wo, nullptr, bo, nullptr, qb, nullptr, nullptr,
                out0 + (size_t)b * NS * NHID);
        }
    }

    ln_kernel<<<dim3(4096), blk, 0, stream>>>(out0, gamma, beta);
    fill_third<<<dim3(4096), blk, 0, stream>>>(out1f);
}

// Round 10
// 391.173 us; speedup vs baseline: 1.1846x; 1.1846x over previous
//
#include <hip/hip_runtime.h>

// Problem constants
#define NB 4
#define NA 3
#define NS 1024
#define NHID 768
#define NHEADS 12
#define HD 64

typedef __bf16 bf16_t;
typedef __bf16 bf16x8 __attribute__((ext_vector_type(8)));
typedef float f32x4 __attribute__((ext_vector_type(4)));

#define MFMA(a, b, c) __builtin_amdgcn_mfma_f32_16x16x32_bf16(a, b, c, 0, 0, 0)

static __device__ __forceinline__ bf16x8 load8(const bf16_t* p) {
    return *reinterpret_cast<const bf16x8*>(p);
}

// async global->LDS, 16B per lane. LDS dest = wave-uniform base + lane*16.
typedef __attribute__((address_space(3))) unsigned int u32_lds;
typedef __attribute__((address_space(1))) unsigned int u32_glb;
static __device__ __forceinline__ void gl_lds16(const void* g, void* lds_base_uniform) {
    __builtin_amdgcn_global_load_lds((const u32_glb*)g, (u32_lds*)lds_base_uniform, 16, 0, 0);
}

static __device__ __forceinline__ bf16x8 cvt8(f32x4 lo, f32x4 hi) {
    bf16x8 r;
    r[0] = (bf16_t)lo[0]; r[1] = (bf16_t)lo[1]; r[2] = (bf16_t)lo[2]; r[3] = (bf16_t)lo[3];
    r[4] = (bf16_t)hi[0]; r[5] = (bf16_t)hi[1]; r[6] = (bf16_t)hi[2]; r[7] = (bf16_t)hi[3];
    return r;
}

// ---------------------------------------------------------------------------
// Projection GEMM, 128x128 tile, BK=32, 4 waves (2x2) of 64x64 (4x4 MFMA).
// R10: fp32 staging switched to ROW-MAJOR XOR pattern (R6-proven correct via
// R6==R7 bit-identity): instr g covers rows g*8+(lane>>3), chunk position
// (lane&7)^(lane>>3) -> 8 CONTIGUOUS 128B segments per instruction instead of
// the half-plane pattern's 64 scattered 16B segments. R8/R9 showed the kernel
// throughput-bound on segment transactions (168us invariant under double
// buffering, MfmaUtil 6.8%). LDS row R holds chunk c at position c^(R&7);
// frag read = R*128 + ((2q)^(R&7))*16 (+^1) — conflict-free per 8-lane phase.
// bf16 A (MODE 3) keeps proven chunk-major pattern. Double-buffered K-loop.
// XCD swizzle: all NT n-tiles of one m-slab on one XCD (bid&7).
// MODE 0: Q bf16 [b][h][s][d]
// MODE 1: fused KV, N=1536: n<768 -> K [b][h][a][s][d]; n>=768 -> VT
// MODE 3: fp32 outf = gemm + bias + resid  (A is bf16 AT)
// ---------------------------------------------------------------------------
template <int MODE, int NT>
__global__ __launch_bounds__(256) void proj_gemm(
    const void* __restrict__ Xv,
    const float* __restrict__ W0, const float* __restrict__ W1,
    const float* __restrict__ bias0, const float* __restrict__ bias1,
    const float* __restrict__ resid,
    bf16_t* __restrict__ out0, bf16_t* __restrict__ out1,
    float* __restrict__ outf)
{
    constexpr bool AF32 = (MODE != 3);
    constexpr int ASZ   = AF32 ? 16384 : 8192;
    constexpr int BUFSZ = ASZ + 16384;
    __shared__ __align__(16) char smem[2 * BUFSZ];

    const int t = threadIdx.x;
    const int lane = t & 63, w = t >> 6;
    const int quad = lane >> 4, l15 = lane & 15;
    const int wm = w >> 1, wn = w & 1;

    // XCD-aware swizzle (bijective index remap)
    const int bid = blockIdx.x;
    const int xcd = bid & 7, jj = bid >> 3;
    const int n_t = jj % NT, slab = jj / NT;
    const int m0 = (slab * 8 + xcd) * 128;
    const int n0 = n_t * 128;

    // B source select (KV fusion)
    const float* Wsel = (MODE == 1 && n0 >= 768) ? W1 : W0;
    const int n0b = (MODE == 1 && n0 >= 768) ? n0 - 768 : n0;

    // hoisted staging pointers — row-major XOR pattern for fp32
    const int srow  = lane >> 3;                 // row within 8-row group
    const int schnk = (lane & 7) ^ srow;         // XOR'd 16B chunk position
    const float* Apf[4];
    const bf16_t* Apb[2];
    const float* Bpf[4];
    if constexpr (AF32) {
        const float* X = (const float*)Xv;
#pragma unroll
        for (int i = 0; i < 4; i++) {
            int g = w * 4 + i;                   // 0..15, 8 rows each
            Apf[i] = X + (size_t)(m0 + g * 8 + srow) * NHID + schnk * 4;
        }
    } else {
        const bf16_t* X = (const bf16_t*)Xv;
#pragma unroll
        for (int i = 0; i < 2; i++) {
            int g = w * 2 + i;                   // chunk-major bf16 (proven)
            Apb[i] = X + (size_t)(m0 + g * 16 + l15) * NHID + quad * 8;
        }
    }
#pragma unroll
    for (int i = 0; i < 4; i++) {
        int g = w * 4 + i;
        Bpf[i] = Wsel + (size_t)(n0b + g * 8 + srow) * NHID + schnk * 4;
    }

    // stage one 32-k tile into buffer `base`, advancing pointers
    auto stage = [&](char* base) {
        char* Ab = base;
        char* Bb = base + ASZ;
        if constexpr (AF32) {
#pragma unroll
            for (int i = 0; i < 4; i++) {
                gl_lds16(Apf[i], Ab + (w * 4 + i) * 1024);
                Apf[i] += 32;
            }
        } else {
#pragma unroll
            for (int i = 0; i < 2; i++) {
                gl_lds16(Apb[i], Ab + (w * 2 + i) * 1024);
                Apb[i] += 32;
            }
        }
#pragma unroll
        for (int i = 0; i < 4; i++) {
            gl_lds16(Bpf[i], Bb + (w * 4 + i) * 1024);
            Bpf[i] += 32;
        }
    };

    f32x4 acc[4][4];
#pragma unroll
    for (int i = 0; i < 4; i++)
#pragma unroll
        for (int j = 0; j < 4; j++) acc[i][j] = 0.0f;

    constexpr int KITER = NHID / 32;   // 24
    stage(smem);
    __syncthreads();

    for (int it = 0; it < KITER; ++it) {
        char* cur = smem + (it & 1) * BUFSZ;
        if (it + 1 < KITER) stage(smem + ((it + 1) & 1) * BUFSZ);

        char* Ab = cur;
        char* Bb = cur + ASZ;
        bf16x8 af[4], bfr[4];
        const int pl = (2 * quad) ^ (l15 & 7);   // XOR'd position of chunk 2q
#pragma unroll
        for (int i = 0; i < 4; i++) {
            if constexpr (AF32) {
                int R = (wm * 4 + i) * 16 + l15;
                f32x4 lo = *(const f32x4*)(Ab + R * 128 + pl * 16);
                f32x4 hi = *(const f32x4*)(Ab + R * 128 + (pl ^ 1) * 16);
                af[i] = cvt8(lo, hi);
            } else {
                int mt = wm * 4 + i;
                af[i] = *(const bf16x8*)(Ab + (mt * 64 + lane) * 16);
            }
        }
#pragma unroll
        for (int j = 0; j < 4; j++) {
            int R = (wn * 4 + j) * 16 + l15;
            f32x4 lo = *(const f32x4*)(Bb + R * 128 + pl * 16);
            f32x4 hi = *(const f32x4*)(Bb + R * 128 + (pl ^ 1) * 16);
            bfr[j] = cvt8(lo, hi);
        }
#pragma unroll
        for (int i = 0; i < 4; i++)
#pragma unroll
            for (int j = 0; j < 4; j++)
                acc[i][j] = MFMA(af[i], bfr[j], acc[i][j]);
        __syncthreads();   // drains next-tile staging; guards buffer reuse
    }

#pragma unroll
    for (int i = 0; i < 4; i++) {
#pragma unroll
        for (int j = 0; j < 4; j++) {
            const int n = n0 + wn * 64 + j * 16 + l15;
            float bn;
            if (MODE == 1) bn = (n < 768) ? bias0[n] : bias1[n - 768];
            else           bn = bias0[n];
#pragma unroll
            for (int rg = 0; rg < 4; rg++) {
                const int m = m0 + wm * 64 + i * 16 + quad * 4 + rg;
                float v = acc[i][j][rg] + bn;
                if (MODE == 0) {
                    int b = m >> 10, s = m & 1023, hh = n >> 6, d = n & 63;
                    out0[(((size_t)(b * NHEADS + hh) * NS) + s) * HD + d] = (bf16_t)v;
                } else if (MODE == 1) {
                    int b = m / (NA * NS);
                    int rem = m - b * (NA * NS);
                    int a = rem >> 10, s = rem & 1023;
                    if (n < 768) {
                        int hh = n >> 6, d = n & 63;
                        out0[((((size_t)(b * NHEADS + hh) * NA + a) * NS) + s) * HD + d] = (bf16_t)v;
                    } else {
                        int hh = (n - 768) >> 6, d = (n - 768) & 63;
                        out1[((((size_t)(b * NHEADS + hh) * NA + a) * HD) + d) * NS + s] = (bf16_t)v;
                    }
                } else {
                    v += resid[(size_t)m * NHID + n];
                    outf[(size_t)m * NHID + n] = v;
                }
            }
        }
    }
}

// ---------------------------------------------------------------------------
// Attention: block = (bh, 64 q-rows); each WAVE owns a distinct 16-row
// q-tile (qt = (qblk<<2)|w). s-tiles of 32 double-buffered via
// global_load_lds; barrier after compute. Staging pointers hoisted.
// XCD swizzle keeps one bh per XCD. (Unchanged from R9.)
// ---------------------------------------------------------------------------
__global__ __launch_bounds__(256) void attn_kernel(
    const bf16_t* __restrict__ Q, const bf16_t* __restrict__ K,
    const bf16_t* __restrict__ VT, bf16_t* __restrict__ AT)
{
    __shared__ __align__(16) char kv[2 * 24576];        // 2 x (K 12K + VT 12K)
    __shared__ __align__(16) bf16_t Pbuf[4][3][16 * 56];

    const int t    = threadIdx.x;
    const int w    = t >> 6, lane = t & 63;
    const int quad = lane >> 4, l15 = lane & 15;

    int bh, qt;
    if (gridDim.x == 768) {           // full launch: XCD-local bh
        int xcd = blockIdx.x & 7, j = blockIdx.x >> 3;
        bh = (j >> 4) * 8 + xcd;      // 6 slabs x 8 xcd = 48
        qt = ((j & 15) << 2) | w;     // wave-level q-tiling: 0..63
    } else {                          // per-batch fallback
        bh = blockIdx.x >> 4;
        qt = ((blockIdx.x & 15) << 2) | w;
    }
    const int b  = bh / NHEADS, h = bh - b * NHEADS;
    const int q0 = qt * 16;

    const bf16_t* Qb = Q + ((size_t)bh * NS + q0) * HD;
    bf16x8 qf0 = load8(Qb + l15 * HD + quad * 8);
    bf16x8 qf1 = load8(Qb + l15 * HD + quad * 8 + 32);

    // hoisted staging pointers: 6 groups per wave (24 total: 12 K + 12 VT)
    const char* gp[6];
    int gdelta[6], loff[6];
#pragma unroll
    for (int i = 0; i < 6; i++) {
        int g = w * 6 + i;
        loff[i] = g >= 12 ? 12288 + (g - 12) * 1024 : g * 1024;
        if (g < 12) {   // K: a|j|dh
            int a = g >> 2, j = (g >> 1) & 1, dh = g & 1;
            gp[i] = (const char*)(K + ((size_t)(bh * NA + a) * NS + j * 16 + l15) * HD
                                  + dh * 32 + quad * 8);
            gdelta[i] = 32 * HD * 2;  // +32 s-rows (bytes)
        } else {        // VT: a|dt
            int gi = g - 12;
            int a = gi >> 2, dt = gi & 3;
            gp[i] = (const char*)(VT + ((size_t)(bh * NA + a) * HD + dt * 16 + l15) * NS
                                  + quad * 8);
            gdelta[i] = 32 * 2;       // +32 s-cols (bytes)
        }
    }

    auto stage = [&](int buf) {
#pragma unroll
        for (int i = 0; i < 6; i++) {
            gl_lds16(gp[i], kv + buf * 24576 + loff[i]);
            gp[i] += gdelta[i];
        }
    };

    f32x4 acc[4];
#pragma unroll
    for (int dt = 0; dt < 4; dt++) acc[dt] = 0.0f;

    const float KS = 0.18033688011112042f;  // (1/8) * log2(e)

    stage(0);
    __syncthreads();

    for (int it = 0; it < 32; ++it) {
        if (it + 1 < 32) stage((it + 1) & 1);

        const char* base = kv + (it & 1) * 24576;
        f32x4 sc[3][2];
#pragma unroll
        for (int a = 0; a < 3; a++) {
#pragma unroll
            for (int j = 0; j < 2; j++) {
                bf16x8 klo = *(const bf16x8*)(base + ((a * 4 + j * 2 + 0) * 64 + lane) * 16);
                bf16x8 khi = *(const bf16x8*)(base + ((a * 4 + j * 2 + 1) * 64 + lane) * 16);
                f32x4 z = 0.0f;
                f32x4 c0 = MFMA(qf0, klo, z);
                sc[a][j] = MFMA(qf1, khi, c0);
            }
        }
        // 3-exp softmax over adapters, write P to LDS (C->A layout transform)
#pragma unroll
        for (int j = 0; j < 2; j++) {
#pragma unroll
            for (int rg = 0; rg < 4; rg++) {
                float x0 = sc[0][j][rg], x1 = sc[1][j][rg], x2 = sc[2][j][rg];
                float mx = fmaxf(x0, fmaxf(x1, x2));
                float e0 = __builtin_amdgcn_exp2f((x0 - mx) * KS);
                float e1 = __builtin_amdgcn_exp2f((x1 - mx) * KS);
                float e2 = __builtin_amdgcn_exp2f((x2 - mx) * KS);
                float inv = __builtin_amdgcn_rcpf(e0 + e1 + e2);
                int pi = (quad * 4 + rg) * 56 + j * 16 + l15;
                Pbuf[w][0][pi] = (bf16_t)(e0 * inv);
                Pbuf[w][1][pi] = (bf16_t)(e1 * inv);
                Pbuf[w][2][pi] = (bf16_t)(e2 * inv);
            }
        }
        // wave-private LDS RAW: drain DS pipe (also compiler fence)
        asm volatile("s_waitcnt lgkmcnt(0)" ::: "memory");
#pragma unroll
        for (int a = 0; a < 3; a++) {
            bf16x8 pf = load8(&Pbuf[w][a][l15 * 56 + quad * 8]);
#pragma unroll
            for (int dt = 0; dt < 4; dt++) {
                bf16x8 vf = *(const bf16x8*)(base + 12288 + ((a * 4 + dt) * 64 + lane) * 16);
                acc[dt] = MFMA(pf, vf, acc[dt]);
            }
        }
        __syncthreads();  // guards buffer reuse; drains it+1 staging
    }

    bf16_t* Ob = AT + (size_t)b * NS * NHID;
#pragma unroll
    for (int dt = 0; dt < 4; dt++) {
#pragma unroll
        for (int rg = 0; rg < 4; rg++) {
            int qq = q0 + quad * 4 + rg;
            Ob[(size_t)qq * NHID + h * HD + dt * 16 + l15] = (bf16_t)acc[dt][rg];
        }
    }
}

// ---------------------------------------------------------------------------
// LayerNorm over rows of X (fp32, [4096,768]), IN PLACE.
// ---------------------------------------------------------------------------
__global__ __launch_bounds__(256) void ln_kernel(
    float* __restrict__ X, const float* __restrict__ gamma,
    const float* __restrict__ beta)
{
    const int row = blockIdx.x;
    const int t = threadIdx.x;
    float* x = X + (size_t)row * NHID;
    float v0 = x[t], v1 = x[t + 256], v2 = x[t + 512];
    float s  = v0 + v1 + v2;
    float s2 = v0 * v0 + v1 * v1 + v2 * v2;
#pragma unroll
    for (int off = 32; off > 0; off >>= 1) {
        s  += __shfl_down(s, off);
        s2 += __shfl_down(s2, off);
    }
    __shared__ float red[8];
    const int w = t >> 6, lane = t & 63;
    if (lane == 0) { red[w] = s; red[4 + w] = s2; }
    __syncthreads();
    s  = red[0] + red[1] + red[2] + red[3];
    s2 = red[4] + red[5] + red[6] + red[7];
    float mu  = s * (1.0f / NHID);
    float var = s2 * (1.0f / NHID) - mu * mu;
    float rs  = rsqrtf(fmaxf(var, 0.0f) + 1e-5f);
    x[t]       = (v0 - mu) * rs * gamma[t]       + beta[t];
    x[t + 256] = (v1 - mu) * rs * gamma[t + 256] + beta[t + 256];
    x[t + 512] = (v2 - mu) * rs * gamma[t + 512] + beta[t + 512];
}

// avg_weights == 1/3 identically (softmax over adapter axis sums to 1).
__global__ __launch_bounds__(256) void fill_third(float* __restrict__ p)
{
    const int i = blockIdx.x * 256 + threadIdx.x;
    f32x4 v = { 1.0f / 3.0f, 1.0f / 3.0f, 1.0f / 3.0f, 1.0f / 3.0f };
    *reinterpret_cast<f32x4*>(p + (size_t)i * 4) = v;
}

// ---------------------------------------------------------------------------
// out0 [0,12.58MB) fp32: O-proj X -> LN in place. out1: bf16 scratch
// (Q 6.29 + AT 6.29 MB), overwritten by fill_third last. ws: K + VT 37.75MB.
// ---------------------------------------------------------------------------
extern "C" void kernel_launch(void* const* d_in, const int* in_sizes, int n_in,
                              void* d_out, int out_size, void* d_ws, size_t ws_size,
                              hipStream_t stream)
{
    (void)in_sizes; (void)n_in; (void)out_size;
    const float* query = (const float*)d_in[0];
    const float* adapt = (const float*)d_in[1];
    const float* Wq    = (const float*)d_in[2];
    const float* bq    = (const float*)d_in[3];
    const float* Wk    = (const float*)d_in[4];
    const float* bk    = (const float*)d_in[5];
    const float* Wv    = (const float*)d_in[6];
    const float* bv    = (const float*)d_in[7];
    const float* Wo    = (const float*)d_in[8];
    const float* bo    = (const float*)d_in[9];
    const float* gamma = (const float*)d_in[10];
    const float* beta  = (const float*)d_in[11];

    float*  out0  = (float*)d_out;            // 3,145,728 fp32
    float*  out1f = out0 + 3145728;           // 4,194,304 fp32
    bf16_t* out1b = (bf16_t*)out1f;

    dim3 blk(256);

    if (ws_size >= (size_t)37748736) {
        bf16_t* Kw  = (bf16_t*)d_ws;
        bf16_t* VTw = (bf16_t*)((char*)d_ws + 18874368);
        bf16_t* Qw  = out1b;
        bf16_t* ATw = out1b + 3145728;
        // Q: M=4096 (32 mt), N=768 (6 nt) -> 192 blocks
        proj_gemm<0, 6><<<dim3(192), blk, 0, stream>>>(
            query, Wq, nullptr, bq, nullptr, nullptr, Qw, nullptr, nullptr);
        // fused KV: M=12288 (96 mt), N=1536 (12 nt) -> 1152 blocks
        proj_gemm<1, 12><<<dim3(1152), blk, 0, stream>>>(
            adapt, Wk, Wv, bk, bv, nullptr, Kw, VTw, nullptr);
        attn_kernel<<<dim3(768), blk, 0, stream>>>(Qw, Kw, VTw, ATw);
        // O: bf16 A, fp32 out + residual
        proj_gemm<3, 6><<<dim3(192), blk, 0, stream>>>(
            ATw, Wo, nullptr, bo, nullptr, query, nullptr, nullptr, out0);
    } else {
        // per-batch, zero-workspace fallback (scratch inside out1)
        bf16_t* Qc  = out1b;                  //   786,432 bf16
        bf16_t* ATc = out1b + 786432;         //   786,432 bf16
        bf16_t* Kc  = out1b + 1572864;        // 2,359,296 bf16
        bf16_t* VTc = out1b + 3932160;        // 2,359,296 bf16
        for (int b = 0; b < NB; b++) {
            const float* qb = query + (size_t)b * NS * NHID;
            const float* ab = adapt + (size_t)b * NA * NS * NHID;
            proj_gemm<0, 6><<<dim3(48), blk, 0, stream>>>(
                qb, Wq, nullptr, bq, nullptr, nullptr, Qc, nullptr, nullptr);
            proj_gemm<1, 12><<<dim3(288), blk, 0, stream>>>(
                ab, Wk, Wv, bk, bv, nullptr, Kc, VTc, nullptr);
            attn_kernel<<<dim3(192), blk, 0, stream>>>(Qc, Kc, VTc, ATc);
            proj_gemm<3, 6><<<dim3(48), blk, 0, stream>>>(
                ATc, Wo, nullptr, bo, nullptr, qb, nullptr, nullptr,
                out0 + (size_t)b * NS * NHID);
        }
    }

    ln_kernel<<<dim3(4096), blk, 0, stream>>>(out0, gamma, beta);
    fill_third<<<dim3(4096), blk, 0, stream>>>(out1f);
}